// Round 2
// baseline (142.383 us; speedup 1.0000x reference)
//
#include <hip/hip_runtime.h>
#include <hip/hip_bf16.h>

#define NN   102      // nodes
#define NE   83       // edges in baked list (pre-filter)
#define NPAD 128      // padded M

using bf16x8 = __attribute__((ext_vector_type(8))) short;   // 8 bf16 (4 VGPRs)
using f32x4  = __attribute__((ext_vector_type(4))) float;   // MFMA C/D

__device__ __constant__ int EDGES_C[NE * 2] = {
    0,6, 0,5, 6,8, 5,7, 0,62, 62,63, 63,64, 59,64, 59,60, 60,61, 61,62,
    0,74, 71,72, 72,73, 73,74, 74,75, 75,76, 76,77, 77,78, 78,79, 79,80,
    80,81, 81,82, 71,82, 71,83, 77,87, 83,84, 84,85, 85,86, 86,87, 87,88,
    88,89, 89,90, 83,90, 0,65, 65,66, 66,67, 67,68, 68,69, 69,70, 65,70,
    7,91, 91,92, 92,93, 93,94, 94,95, 91,96, 96,97, 97,98, 98,99, 91,100,
    100,101, 101,102, 102,103, 91,104, 104,105, 105,106, 106,107, 91,108,
    108,109, 109,110, 110,111, 8,112, 112,113, 113,114, 114,115, 115,116,
    112,117, 117,118, 118,119, 119,120, 112,121, 121,122, 122,123, 123,124,
    112,125, 125,126, 126,127, 127,128, 112,129, 129,130, 130,131, 131,132
};

// ws layout (bytes)
#define WS_BFRAG 0                   // 16 frags * 64 lanes * 16B = 16384
#define WS_OFF   16384               // 103 ints (padded to 512)
#define WS_ER    (16384 + 512)       // up to 256 ints
#define WS_EN    (16384 + 512 + 1024)// up to 256 floats

__device__ inline unsigned short f2bf(float f) {
  union { float f; unsigned u; } v; v.f = f;
  unsigned r = v.u + 0x7fffu + ((v.u >> 16) & 1u);   // RNE
  return (unsigned short)(r >> 16);
}

// HW packed f32->bf16 convert (2 elems / instr)
__device__ inline unsigned cvt_pk_bf16(float lo, float hi) {
  unsigned r;
  asm("v_cvt_pk_bf16_f32 %0, %1, %2" : "=v"(r) : "v"(lo), "v"(hi));
  return r;
}

// One small block: builds normalized-graph CSR + per-lane bf16 Wp^T fragments.
// Fragment f = mt*2+kc: lane holds Wp[k][e], e = mt*16+(lane&15),
// k = kc*32 + (lane>>4)*8 + i  -- serves as the MFMA A-operand (out^T = Wp^T * act^T).
__global__ void gnn_setup(const float* __restrict__ Wp, char* __restrict__ ws) {
  __shared__ float s_dinv[NN];
  __shared__ int   s_cnt[NN];
  __shared__ int   s_off[NN + 1];
  const int t = threadIdx.x;

  if (t < NN) {
    int deg = 1, cnt = 1;                       // self loop
    for (int e = 0; e < NE; ++e) {
      int r = EDGES_C[2*e], c = EDGES_C[2*e+1];
      if (r < NN && c == t) { ++deg; ++cnt; }
    }
    s_dinv[t] = 1.0f / sqrtf((float)deg);
    s_cnt[t]  = cnt;
  }
  __syncthreads();
  if (t < NN) {
    int o = 0;
    for (int c = 0; c < t; ++c) o += s_cnt[c];
    s_off[t] = o;
    if (t == NN - 1) s_off[NN] = o + s_cnt[t];
  }
  __syncthreads();
  int*   off = (int*)(ws + WS_OFF);
  int*   er  = (int*)(ws + WS_ER);
  float* en  = (float*)(ws + WS_EN);
  if (t < NN) {
    int c = t, pos = s_off[c];
    float dc = s_dinv[c];
    er[pos] = c; en[pos] = dc * dc; ++pos;      // self loop
    for (int e = 0; e < NE; ++e) {
      int r = EDGES_C[2*e], cc = EDGES_C[2*e+1];
      if (r < NN && cc == c) { er[pos] = r; en[pos] = s_dinv[r] * dc; ++pos; }
    }
    off[c] = s_off[c];
    if (c == 0) off[NN] = s_off[NN];
  }
  unsigned short* bf = (unsigned short*)(ws + WS_BFRAG);
  for (int idx = t; idx < 16 * 64; idx += blockDim.x) {
    int lane = idx & 63;
    int f    = idx >> 6;          // f = mt*2 + kc
    int mt   = f >> 1, kc = f & 1;
    int e    = mt * 16 + (lane & 15);
    int kb   = kc * 32 + (lane >> 4) * 8;
    unsigned short* dst = bf + idx * 8;
#pragma unroll
    for (int i = 0; i < 8; ++i) dst[i] = f2bf(Wp[(kb + i) * 128 + e]);
  }
}

// One block per batch element; 4 waves.
// Swapped-operand MFMA: D = Wp^T(16e x 32k) * act^T(32k x 16node) -> out^T tile.
// C/D layout (m89): lane holds D[e = mt*16 + (lane>>4)*4 + j][node = nt*16 + (lane&15)]
//   -> 4 consecutive e per lane = one float4 store into out[b][node][e..e+3].
// Waves partition node-tiles: wave wv owns nt = 2wv, 2wv+1 (nt=7 is all-padding, skipped).
__global__ __launch_bounds__(256) void gnn_main(
    const float* __restrict__ x, const float* __restrict__ Wg,
    const float* __restrict__ bg, const float* __restrict__ bp,
    const char* __restrict__ ws, float* __restrict__ out) {
  const int b    = blockIdx.x;
  const int t    = threadIdx.x;
  const int lane = t & 63;
  const int wv   = t >> 6;

  __shared__ float sx[204];
  __shared__ float sy[NPAD][2];
  __shared__ float swg[128];
  __shared__ float sbg[64];
  __shared__ float sbp[128];

  if (t < 204) sx[t] = x[(size_t)b * 204 + t];
  if (t < 128) { swg[t] = Wg[t]; sbp[t] = bp[t]; }
  if (t < 64)  sbg[t] = bg[t];
  __syncthreads();

  // y = S @ xn[b]   (CSR, ~1.5 nnz/row avg); sy zero-padded to 128
  if (t < NPAD) {
    float y0 = 0.f, y1 = 0.f;
    if (t < NN) {
      const int*   off = (const int*)(ws + WS_OFF);
      const int*   er  = (const int*)(ws + WS_ER);
      const float* en  = (const float*)(ws + WS_EN);
      int s = off[t], e2 = off[t + 1];
      for (int j = s; j < e2; ++j) {
        int r = er[j]; float w = en[j];
        y0 = fmaf(w, sx[2 * r],     y0);
        y1 = fmaf(w, sx[2 * r + 1], y1);
      }
    }
    sy[t][0] = y0; sy[t][1] = y1;
  }
  __syncthreads();

  const int l15 = lane & 15;
  const int lhi = lane >> 4;
  const int kb  = lhi * 8;     // k offset within a 32-wide kc chunk
  const int rb  = lhi * 4;     // C/D row (=e) offset

  // B-operand: act^T fragments for this wave's two node tiles (in registers).
  // lane holds act[node][k], node = nt*16+(lane&15), k = kc*32+kb+i.
  bf16x8 Bact[2][2];
#pragma unroll
  for (int nl = 0; nl < 2; ++nl)
#pragma unroll
    for (int kc = 0; kc < 2; ++kc) {
      bf16x8 z = {0,0,0,0,0,0,0,0};
      Bact[nl][kc] = z;
    }

  const int nt0 = wv * 2;
#pragma unroll
  for (int nl = 0; nl < 2; ++nl) {
    const int nt = nt0 + nl;
    if (nt >= 7) continue;                       // tile of pure padding
    const int node = nt * 16 + l15;
    const float y0 = sy[node][0], y1 = sy[node][1];
#pragma unroll
    for (int kc = 0; kc < 2; ++kc) {
      float v[8];
#pragma unroll
      for (int i = 0; i < 8; ++i) {
        int h = kc * 32 + kb + i;
        float a = fmaf(y0, swg[h], fmaf(y1, swg[64 + h], sbg[h]));
        v[i] = fmaxf(a, 0.f);
      }
      unsigned p0 = cvt_pk_bf16(v[0], v[1]);
      unsigned p1 = cvt_pk_bf16(v[2], v[3]);
      unsigned p2 = cvt_pk_bf16(v[4], v[5]);
      unsigned p3 = cvt_pk_bf16(v[6], v[7]);
      union { unsigned u[4]; bf16x8 f; } pk;
      pk.u[0] = p0; pk.u[1] = p1; pk.u[2] = p2; pk.u[3] = p3;
      Bact[nl][kc] = pk.f;
    }
  }

  // A-operand: Wp^T fragments from ws (block-invariant, L2-resident)
  const bf16x8* bfr = (const bf16x8*)(ws + WS_BFRAG);
  bf16x8 Apf[8][2];
#pragma unroll
  for (int mt = 0; mt < 8; ++mt) {
    Apf[mt][0] = bfr[(mt * 2 + 0) * 64 + lane];
    Apf[mt][1] = bfr[(mt * 2 + 1) * 64 + lane];
  }

  // acc init = bias (C-in carries b_proj): acc[mt][nl][j] = bp[mt*16 + rb + j]
  f32x4 acc[8][2];
#pragma unroll
  for (int mt = 0; mt < 8; ++mt) {
    f32x4 bb = *(const f32x4*)&sbp[mt * 16 + rb];
    acc[mt][0] = bb;
    acc[mt][1] = bb;
  }

#pragma unroll
  for (int mt = 0; mt < 8; ++mt)
#pragma unroll
    for (int nl = 0; nl < 2; ++nl) {
      if (nt0 + nl >= 7) continue;
#pragma unroll
      for (int kc = 0; kc < 2; ++kc)
        acc[mt][nl] = __builtin_amdgcn_mfma_f32_16x16x32_bf16(
            Apf[mt][kc], Bact[nl][kc], acc[mt][nl], 0, 0, 0);
    }

  // Epilogue: one float4 per (mt, nl) -> out[b][node][mt*16+rb .. +3]
#pragma unroll
  for (int nl = 0; nl < 2; ++nl) {
    const int nt = nt0 + nl;
    if (nt >= 7) continue;
    const int node = nt * 16 + l15;
    if (node < NN) {
      float* op = out + ((size_t)b * NN + node) * 128 + rb;
#pragma unroll
      for (int mt = 0; mt < 8; ++mt)
        *(f32x4*)(op + mt * 16) = acc[mt][nl];
    }
  }
}

extern "C" void kernel_launch(void* const* d_in, const int* in_sizes, int n_in,
                              void* d_out, int out_size, void* d_ws, size_t ws_size,
                              hipStream_t stream) {
  const float* x  = (const float*)d_in[0];   // (B, 204)
  const float* Wg = (const float*)d_in[1];   // (2, 64)
  const float* bg = (const float*)d_in[2];   // (64,)
  const float* Wp = (const float*)d_in[3];   // (64, 128)
  const float* bp = (const float*)d_in[4];   // (128,)
  float* out = (float*)d_out;                // (B, 102, 128)
  const int B = in_sizes[0] / 204;

  gnn_setup<<<1, 256, 0, stream>>>(Wp, (char*)d_ws);
  gnn_main<<<B, 256, 0, stream>>>(x, Wg, bg, bp, (const char*)d_ws, out);
}

// Round 3
// 118.484 us; speedup vs baseline: 1.2017x; 1.2017x over previous
//
#include <hip/hip_runtime.h>
#include <hip/hip_bf16.h>

#define NN   102      // nodes
#define NE   83       // edges in baked list (pre-filter)
#define NPAD 128      // padded M

using bf16x8 = __attribute__((ext_vector_type(8))) short;   // 8 bf16 (4 VGPRs)
using f32x4  = __attribute__((ext_vector_type(4))) float;   // MFMA C/D

__device__ __constant__ int EDGES_C[NE * 2] = {
    0,6, 0,5, 6,8, 5,7, 0,62, 62,63, 63,64, 59,64, 59,60, 60,61, 61,62,
    0,74, 71,72, 72,73, 73,74, 74,75, 75,76, 76,77, 77,78, 78,79, 79,80,
    80,81, 81,82, 71,82, 71,83, 77,87, 83,84, 84,85, 85,86, 86,87, 87,88,
    88,89, 89,90, 83,90, 0,65, 65,66, 66,67, 67,68, 68,69, 69,70, 65,70,
    7,91, 91,92, 92,93, 93,94, 94,95, 91,96, 96,97, 97,98, 98,99, 91,100,
    100,101, 101,102, 102,103, 91,104, 104,105, 105,106, 106,107, 91,108,
    108,109, 109,110, 110,111, 8,112, 112,113, 113,114, 114,115, 115,116,
    112,117, 117,118, 118,119, 119,120, 112,121, 121,122, 122,123, 123,124,
    112,125, 125,126, 126,127, 127,128, 112,129, 129,130, 130,131, 131,132
};

// ws layout (bytes)
#define WS_BFRAG 0                   // 16 frags * 64 lanes * 16B = 16384
#define WS_OFF   16384               // 103 ints (padded to 512)
#define WS_ER    (16384 + 512)       // up to 256 ints
#define WS_EN    (16384 + 512 + 1024)// up to 256 floats

__device__ inline unsigned short f2bf(float f) {
  union { float f; unsigned u; } v; v.f = f;
  unsigned r = v.u + 0x7fffu + ((v.u >> 16) & 1u);   // RNE
  return (unsigned short)(r >> 16);
}

// HW packed f32->bf16 convert (2 elems / instr)
__device__ inline unsigned cvt_pk_bf16(float lo, float hi) {
  unsigned r;
  asm("v_cvt_pk_bf16_f32 %0, %1, %2" : "=v"(r) : "v"(lo), "v"(hi));
  return r;
}

// One small block: builds normalized-graph CSR + per-lane bf16 Wp^T fragments.
// Fragment f = mt*2+kc: lane holds Wp[k][e], e = mt*16+(lane&15),
// k = kc*32 + (lane>>4)*8 + i  -- serves as the MFMA A-operand (out^T = Wp^T * act^T).
__global__ void gnn_setup(const float* __restrict__ Wp, char* __restrict__ ws) {
  __shared__ float s_dinv[NN];
  __shared__ int   s_cnt[NN];
  __shared__ int   s_off[NN + 1];
  const int t = threadIdx.x;

  if (t < NN) {
    int deg = 1, cnt = 1;                       // self loop
    for (int e = 0; e < NE; ++e) {
      int r = EDGES_C[2*e], c = EDGES_C[2*e+1];
      if (r < NN && c == t) { ++deg; ++cnt; }
    }
    s_dinv[t] = 1.0f / sqrtf((float)deg);
    s_cnt[t]  = cnt;
  }
  __syncthreads();
  if (t < NN) {
    int o = 0;
    for (int c = 0; c < t; ++c) o += s_cnt[c];
    s_off[t] = o;
    if (t == NN - 1) s_off[NN] = o + s_cnt[t];
  }
  __syncthreads();
  int*   off = (int*)(ws + WS_OFF);
  int*   er  = (int*)(ws + WS_ER);
  float* en  = (float*)(ws + WS_EN);
  if (t < NN) {
    int c = t, pos = s_off[c];
    float dc = s_dinv[c];
    er[pos] = c; en[pos] = dc * dc; ++pos;      // self loop
    for (int e = 0; e < NE; ++e) {
      int r = EDGES_C[2*e], cc = EDGES_C[2*e+1];
      if (r < NN && cc == c) { er[pos] = r; en[pos] = s_dinv[r] * dc; ++pos; }
    }
    off[c] = s_off[c];
    if (c == 0) off[NN] = s_off[NN];
  }
  unsigned short* bf = (unsigned short*)(ws + WS_BFRAG);
  for (int idx = t; idx < 16 * 64; idx += blockDim.x) {
    int lane = idx & 63;
    int f    = idx >> 6;          // f = mt*2 + kc
    int mt   = f >> 1, kc = f & 1;
    int e    = mt * 16 + (lane & 15);
    int kb   = kc * 32 + (lane >> 4) * 8;
    unsigned short* dst = bf + idx * 8;
#pragma unroll
    for (int i = 0; i < 8; ++i) dst[i] = f2bf(Wp[(kb + i) * 128 + e]);
  }
}

// One block per batch element; 4 waves.
// Swapped-operand MFMA: D = Wp^T(16e x 32k) * act^T(32k x 16node) -> out^T tile.
// C/D layout (m89): lane holds D[e = mt*16 + (lane>>4)*4 + j][node = nt*16 + (lane&15)].
// Epilogue transposes through a per-wave LDS slab so every global store is
// 2 complete contiguous 512B output rows (full 128B lines -> no write-allocate RMW).
__global__ __launch_bounds__(256) void gnn_main(
    const float* __restrict__ x, const float* __restrict__ Wg,
    const float* __restrict__ bg, const float* __restrict__ bp,
    const char* __restrict__ ws, float* __restrict__ out) {
  const int b    = blockIdx.x;
  const int t    = threadIdx.x;
  const int lane = t & 63;
  const int wv   = t >> 6;

  __shared__ float sx[204];
  __shared__ float sy[NPAD][2];
  __shared__ float swg[128];
  __shared__ float sbg[64];
  __shared__ float sbp[128];
  __shared__ float st[4][16][132];   // per-wave transpose slab, stride 132 (132 mod 32 = 4)

  if (t < 204) sx[t] = x[(size_t)b * 204 + t];
  if (t < 128) { swg[t] = Wg[t]; sbp[t] = bp[t]; }
  if (t < 64)  sbg[t] = bg[t];
  __syncthreads();

  // y = S @ xn[b]   (CSR, ~1.5 nnz/row avg); sy zero-padded to 128
  if (t < NPAD) {
    float y0 = 0.f, y1 = 0.f;
    if (t < NN) {
      const int*   off = (const int*)(ws + WS_OFF);
      const int*   er  = (const int*)(ws + WS_ER);
      const float* en  = (const float*)(ws + WS_EN);
      int s = off[t], e2 = off[t + 1];
      for (int j = s; j < e2; ++j) {
        int r = er[j]; float w = en[j];
        y0 = fmaf(w, sx[2 * r],     y0);
        y1 = fmaf(w, sx[2 * r + 1], y1);
      }
    }
    sy[t][0] = y0; sy[t][1] = y1;
  }
  __syncthreads();

  const int l15 = lane & 15;
  const int lhi = lane >> 4;
  const int kb  = lhi * 8;     // k offset within a 32-wide kc chunk
  const int rb  = lhi * 4;     // C/D row (=e) offset

  // B-operand: act^T fragments for this wave's two node tiles (in registers).
  bf16x8 Bact[2][2];
#pragma unroll
  for (int nl = 0; nl < 2; ++nl)
#pragma unroll
    for (int kc = 0; kc < 2; ++kc) {
      bf16x8 z = {0,0,0,0,0,0,0,0};
      Bact[nl][kc] = z;
    }

  const int nt0 = wv * 2;
#pragma unroll
  for (int nl = 0; nl < 2; ++nl) {
    const int nt = nt0 + nl;
    if (nt >= 7) continue;                       // tile of pure padding
    const int node = nt * 16 + l15;
    const float y0 = sy[node][0], y1 = sy[node][1];
#pragma unroll
    for (int kc = 0; kc < 2; ++kc) {
      float v[8];
#pragma unroll
      for (int i = 0; i < 8; ++i) {
        int h = kc * 32 + kb + i;
        float a = fmaf(y0, swg[h], fmaf(y1, swg[64 + h], sbg[h]));
        v[i] = fmaxf(a, 0.f);
      }
      union { unsigned u[4]; bf16x8 f; } pk;
      pk.u[0] = cvt_pk_bf16(v[0], v[1]);
      pk.u[1] = cvt_pk_bf16(v[2], v[3]);
      pk.u[2] = cvt_pk_bf16(v[4], v[5]);
      pk.u[3] = cvt_pk_bf16(v[6], v[7]);
      Bact[nl][kc] = pk.f;
    }
  }

  // A-operand: Wp^T fragments from ws (block-invariant, L2-resident)
  const bf16x8* bfr = (const bf16x8*)(ws + WS_BFRAG);
  bf16x8 Apf[8][2];
#pragma unroll
  for (int mt = 0; mt < 8; ++mt) {
    Apf[mt][0] = bfr[(mt * 2 + 0) * 64 + lane];
    Apf[mt][1] = bfr[(mt * 2 + 1) * 64 + lane];
  }

  // acc init = bias (C-in carries b_proj): acc[mt][nl][j] = bp[mt*16 + rb + j]
  f32x4 acc[8][2];
#pragma unroll
  for (int mt = 0; mt < 8; ++mt) {
    f32x4 bb = *(const f32x4*)&sbp[mt * 16 + rb];
    acc[mt][0] = bb;
    acc[mt][1] = bb;
  }

#pragma unroll
  for (int mt = 0; mt < 8; ++mt)
#pragma unroll
    for (int nl = 0; nl < 2; ++nl) {
      if (nt0 + nl >= 7) continue;
#pragma unroll
      for (int kc = 0; kc < 2; ++kc)
        acc[mt][nl] = __builtin_amdgcn_mfma_f32_16x16x32_bf16(
            Apf[mt][kc], Bact[nl][kc], acc[mt][nl], 0, 0, 0);
    }

  // Epilogue: per-wave LDS transpose -> full-line contiguous stores.
  // No __syncthreads needed: each wave uses its private slab; intra-wave
  // LDS ordering is handled by compiler-inserted lgkmcnt waits.
  const int c32 = (lane & 31) * 4;          // read column (floats)
  const int rhi = lane >> 5;                // 0/1: which of 2 rows per pass
#pragma unroll
  for (int nl = 0; nl < 2; ++nl) {
    const int nt = nt0 + nl;
    if (nt >= 7) continue;
    // write acc -> slab: st[wv][l15][mt*16 + rb .. +3]
#pragma unroll
    for (int mt = 0; mt < 8; ++mt)
      *(f32x4*)&st[wv][l15][mt * 16 + rb] = acc[mt][nl];
    // read 2 full rows per pass, store 1KB contiguous
#pragma unroll
    for (int pass = 0; pass < 8; ++pass) {
      const int n2   = pass * 2 + rhi;
      const int node = nt * 16 + n2;
      if (node < NN) {
        f32x4 row = *(const f32x4*)&st[wv][n2][c32];
        *(f32x4*)(out + ((size_t)b * NN + node) * 128 + c32) = row;
      }
    }
  }
}

extern "C" void kernel_launch(void* const* d_in, const int* in_sizes, int n_in,
                              void* d_out, int out_size, void* d_ws, size_t ws_size,
                              hipStream_t stream) {
  const float* x  = (const float*)d_in[0];   // (B, 204)
  const float* Wg = (const float*)d_in[1];   // (2, 64)
  const float* bg = (const float*)d_in[2];   // (64,)
  const float* Wp = (const float*)d_in[3];   // (64, 128)
  const float* bp = (const float*)d_in[4];   // (128,)
  float* out = (float*)d_out;                // (B, 102, 128)
  const int B = in_sizes[0] / 204;

  gnn_setup<<<1, 256, 0, stream>>>(Wp, (char*)d_ws);
  gnn_main<<<B, 256, 0, stream>>>(x, Wg, bg, bp, (const char*)d_ws, out);
}

// Round 4
// 108.856 us; speedup vs baseline: 1.3080x; 1.0885x over previous
//
#include <hip/hip_runtime.h>
#include <hip/hip_bf16.h>

#define NN   102      // nodes
#define NE   83       // edges in baked list (pre-filter)
#define NPAD 128      // padded node count

using bf16x8 = __attribute__((ext_vector_type(8))) short;   // 8 bf16 (4 VGPRs)
using f32x4  = __attribute__((ext_vector_type(4))) float;   // MFMA C/D

__device__ __constant__ int EDGES_C[NE * 2] = {
    0,6, 0,5, 6,8, 5,7, 0,62, 62,63, 63,64, 59,64, 59,60, 60,61, 61,62,
    0,74, 71,72, 72,73, 73,74, 74,75, 75,76, 76,77, 77,78, 78,79, 79,80,
    80,81, 81,82, 71,82, 71,83, 77,87, 83,84, 84,85, 85,86, 86,87, 87,88,
    88,89, 89,90, 83,90, 0,65, 65,66, 66,67, 67,68, 68,69, 69,70, 65,70,
    7,91, 91,92, 92,93, 93,94, 94,95, 91,96, 96,97, 97,98, 98,99, 91,100,
    100,101, 101,102, 102,103, 91,104, 104,105, 105,106, 106,107, 91,108,
    108,109, 109,110, 110,111, 8,112, 112,113, 113,114, 114,115, 115,116,
    112,117, 117,118, 118,119, 119,120, 112,121, 121,122, 122,123, 123,124,
    112,125, 125,126, 126,127, 127,128, 112,129, 129,130, 130,131, 131,132
};

// ws layout (bytes)
#define WS_BFRAG 0                   // 16 frags * 64 lanes * 16B = 16384
#define WS_OFF   16384               // 103 ints (padded to 512)
#define WS_ER    (16384 + 512)       // up to 256 ints
#define WS_EN    (16384 + 512 + 1024)// up to 256 floats

__device__ inline unsigned short f2bf(float f) {
  union { float f; unsigned u; } v; v.f = f;
  unsigned r = v.u + 0x7fffu + ((v.u >> 16) & 1u);   // RNE
  return (unsigned short)(r >> 16);
}

// HW packed f32->bf16 convert (2 elems / instr)
__device__ inline unsigned cvt_pk_bf16(float lo, float hi) {
  unsigned r;
  asm("v_cvt_pk_bf16_f32 %0, %1, %2" : "=v"(r) : "v"(lo), "v"(hi));
  return r;
}

// One small block: builds normalized-graph CSR + per-lane bf16 Wp^T fragments.
// Fragment f = mt*2+kc: lane holds Wp[k][e], e = mt*16+(lane&15),
// k = kc*32 + (lane>>4)*8 + i  -- serves as the MFMA A-operand (out^T = Wp^T * act^T).
__global__ void gnn_setup(const float* __restrict__ Wp, char* __restrict__ ws) {
  __shared__ float s_dinv[NN];
  __shared__ int   s_cnt[NN];
  __shared__ int   s_off[NN + 1];
  const int t = threadIdx.x;

  if (t < NN) {
    int deg = 1, cnt = 1;                       // self loop
    for (int e = 0; e < NE; ++e) {
      int r = EDGES_C[2*e], c = EDGES_C[2*e+1];
      if (r < NN && c == t) { ++deg; ++cnt; }
    }
    s_dinv[t] = 1.0f / sqrtf((float)deg);
    s_cnt[t]  = cnt;
  }
  __syncthreads();
  if (t < NN) {
    int o = 0;
    for (int c = 0; c < t; ++c) o += s_cnt[c];
    s_off[t] = o;
    if (t == NN - 1) s_off[NN] = o + s_cnt[t];
  }
  __syncthreads();
  int*   off = (int*)(ws + WS_OFF);
  int*   er  = (int*)(ws + WS_ER);
  float* en  = (float*)(ws + WS_EN);
  if (t < NN) {
    int c = t, pos = s_off[c];
    float dc = s_dinv[c];
    er[pos] = c; en[pos] = dc * dc; ++pos;      // self loop
    for (int e = 0; e < NE; ++e) {
      int r = EDGES_C[2*e], cc = EDGES_C[2*e+1];
      if (r < NN && cc == c) { er[pos] = r; en[pos] = s_dinv[r] * dc; ++pos; }
    }
    off[c] = s_off[c];
    if (c == 0) off[NN] = s_off[NN];
  }
  unsigned short* bf = (unsigned short*)(ws + WS_BFRAG);
  for (int idx = t; idx < 16 * 64; idx += blockDim.x) {
    int lane = idx & 63;
    int f    = idx >> 6;          // f = mt*2 + kc
    int mt   = f >> 1, kc = f & 1;
    int e    = mt * 16 + (lane & 15);
    int kb   = kc * 32 + (lane >> 4) * 8;
    unsigned short* dst = bf + idx * 8;
#pragma unroll
    for (int i = 0; i < 8; ++i) dst[i] = f2bf(Wp[(kb + i) * 128 + e]);
  }
}

// ONE WAVE = ONE BATCH ELEMENT. 4 independent waves per block, each with a
// private LDS slice; the only barrier is at kernel start (shared constants).
// Swapped-operand MFMA: D = Wp^T(16e x 32k) * act^T(32k x 16node) -> out^T tile.
// C/D (m89): lane holds D[e = mt*16+(lane>>4)*4+j][node = nt*16+(lane&15)].
// Per-wave LDS transpose -> every global store = 1KB contiguous (2 full rows).
__global__ __launch_bounds__(256) void gnn_main(
    const float* __restrict__ x, const float* __restrict__ Wg,
    const float* __restrict__ bg, const float* __restrict__ bp,
    const char* __restrict__ ws, float* __restrict__ out, int B) {
  const int t    = threadIdx.x;
  const int lane = t & 63;
  const int wv   = t >> 6;
  const int b    = blockIdx.x * 4 + wv;

  __shared__ float swg[128];
  __shared__ float sbg[64];
  __shared__ float sbp[128];
  __shared__ float sxw[4][208];        // per-wave x slab
  __shared__ float syw[4][NPAD][2];    // per-wave y slab (zero-padded)
  __shared__ float st[4][16][132];     // per-wave transpose slab

  if (t < 128) { swg[t] = Wg[t]; sbp[t] = bp[t]; }
  if (t < 64)  sbg[t] = bg[t];
  __syncthreads();                     // the only block-wide barrier

  if (b >= B) return;

  float* sx = sxw[wv];
  float (*sy)[2] = syw[wv];

  // per-wave x load: 51 lanes x 16B = 204 floats
  if (lane < 51)
    *(f32x4*)&sx[lane * 4] = *(const f32x4*)(x + (size_t)b * 204 + lane * 4);

  // y = S @ xn[b]; each lane covers nodes (lane) and (lane+64); pad rows zeroed.
  {
    const int*   off = (const int*)(ws + WS_OFF);
    const int*   er  = (const int*)(ws + WS_ER);
    const float* en  = (const float*)(ws + WS_EN);
#pragma unroll
    for (int half = 0; half < 2; ++half) {
      const int n = lane + half * 64;
      float y0 = 0.f, y1 = 0.f;
      if (n < NN) {
        int s = off[n], e2 = off[n + 1];
        for (int j = s; j < e2; ++j) {
          int r = er[j]; float w = en[j];
          y0 = fmaf(w, sx[2 * r],     y0);
          y1 = fmaf(w, sx[2 * r + 1], y1);
        }
      }
      sy[n][0] = y0; sy[n][1] = y1;
    }
  }

  const int l15 = lane & 15;
  const int lhi = lane >> 4;
  const int kb  = lhi * 8;     // k offset within a 32-wide kc chunk
  const int rb  = lhi * 4;     // C/D row (=e) offset
  const int c32 = (lane & 31) * 4;
  const int rhi = lane >> 5;

  // A-operand: Wp^T fragments (block-invariant, L2-resident), persistent
  const bf16x8* bfr = (const bf16x8*)(ws + WS_BFRAG);
  bf16x8 Apf[8][2];
#pragma unroll
  for (int mt = 0; mt < 8; ++mt) {
    Apf[mt][0] = bfr[(mt * 2 + 0) * 64 + lane];
    Apf[mt][1] = bfr[(mt * 2 + 1) * 64 + lane];
  }
  // bias as C-in
  f32x4 bias[8];
#pragma unroll
  for (int mt = 0; mt < 8; ++mt)
    bias[mt] = *(const f32x4*)&sbp[mt * 16 + rb];

  float* ob = out + (size_t)b * (NN * 128);

  for (int nt = 0; nt < 7; ++nt) {
    // B-operand: act^T fragment for node tile nt
    const int node = nt * 16 + l15;
    const float y0 = sy[node][0], y1 = sy[node][1];
    bf16x8 Bact[2];
#pragma unroll
    for (int kc = 0; kc < 2; ++kc) {
      float v[8];
#pragma unroll
      for (int i = 0; i < 8; ++i) {
        int h = kc * 32 + kb + i;
        float a = fmaf(y0, swg[h], fmaf(y1, swg[64 + h], sbg[h]));
        v[i] = fmaxf(a, 0.f);
      }
      union { unsigned u[4]; bf16x8 f; } pk;
      pk.u[0] = cvt_pk_bf16(v[0], v[1]);
      pk.u[1] = cvt_pk_bf16(v[2], v[3]);
      pk.u[2] = cvt_pk_bf16(v[4], v[5]);
      pk.u[3] = cvt_pk_bf16(v[6], v[7]);
      Bact[kc] = pk.f;
    }

    f32x4 acc[8];
#pragma unroll
    for (int mt = 0; mt < 8; ++mt) acc[mt] = bias[mt];
#pragma unroll
    for (int mt = 0; mt < 8; ++mt)
#pragma unroll
      for (int kc = 0; kc < 2; ++kc)
        acc[mt] = __builtin_amdgcn_mfma_f32_16x16x32_bf16(
            Apf[mt][kc], Bact[kc], acc[mt], 0, 0, 0);

    // transpose through private slab
#pragma unroll
    for (int mt = 0; mt < 8; ++mt)
      *(f32x4*)&st[wv][l15][mt * 16 + rb] = acc[mt];

    const int rows = (nt < 6) ? 16 : (NN - 96);   // 16 or 6
#pragma unroll
    for (int pass = 0; pass < 8; ++pass) {
      const int n2 = pass * 2 + rhi;
      if (n2 < rows) {
        f32x4 row = *(const f32x4*)&st[wv][n2][c32];
        *(f32x4*)(ob + (nt * 16 + n2) * 128 + c32) = row;
      }
    }
  }
}

extern "C" void kernel_launch(void* const* d_in, const int* in_sizes, int n_in,
                              void* d_out, int out_size, void* d_ws, size_t ws_size,
                              hipStream_t stream) {
  const float* x  = (const float*)d_in[0];   // (B, 204)
  const float* Wg = (const float*)d_in[1];   // (2, 64)
  const float* bg = (const float*)d_in[2];   // (64,)
  const float* Wp = (const float*)d_in[3];   // (64, 128)
  const float* bp = (const float*)d_in[4];   // (128,)
  float* out = (float*)d_out;                // (B, 102, 128)
  const int B = in_sizes[0] / 204;

  gnn_setup<<<1, 256, 0, stream>>>(Wp, (char*)d_ws);
  gnn_main<<<(B + 3) / 4, 256, 0, stream>>>(x, Wg, bg, bp, (const char*)d_ws, out, B);
}